// Round 3
// baseline (201.379 us; speedup 1.0000x reference)
//
#include <hip/hip_runtime.h>
#include <math.h>

#define N_EMB 1024
#define D_EMB 512
#define EPS_Q 1e-10f

// One block (256 threads = 4 waves) per (b,s) row.
// Each thread owns 4 consecutive elements of the N=1024 row (float4).
__global__ __launch_bounds__(256) void gumbel_quantize_kernel(
    const float* __restrict__ logits,   // [rows, 1024]
    const float* __restrict__ u,        // [rows, 1024]
    const float* __restrict__ embed,    // [1024, 512]
    float*       __restrict__ zq,       // [rows, 512]
    float*       __restrict__ diff,     // [rows, 1024]
    float*       __restrict__ indf)     // [rows] (int stored as float)
{
    const int row  = blockIdx.x;
    const int t    = threadIdx.x;
    const int lane = t & 63;
    const int wave = t >> 6;
    const size_t rbase = (size_t)row * N_EMB;

    const float4 l4 = ((const float4*)(logits + rbase))[t];
    const float4 u4 = ((const float4*)(u      + rbase))[t];

    float lv[4] = {l4.x, l4.y, l4.z, l4.w};
    float uv[4] = {u4.x, u4.y, u4.z, u4.w};

    // ---- per-thread: gumbel-perturbed score argmax + logit max ----
    float smax = -INFINITY; int sidx = 0;
    float lmax = -INFINITY;
    #pragma unroll
    for (int j = 0; j < 4; ++j) {
        const float g  = -logf(-logf(uv[j]));       // gumbel noise
        const float sc = lv[j] + g;                 // tau == 1.0
        const int   idx = t * 4 + j;
        if (sc > smax) { smax = sc; sidx = idx; }   // first-index on ties
        lmax = fmaxf(lmax, lv[j]);
    }

    // ---- wave (64-lane) butterfly reduce: argmax(score), max(logit) ----
    #pragma unroll
    for (int off = 32; off > 0; off >>= 1) {
        const float v2 = __shfl_xor(smax, off, 64);
        const int   i2 = __shfl_xor(sidx, off, 64);
        if (v2 > smax || (v2 == smax && i2 < sidx)) { smax = v2; sidx = i2; }
        lmax = fmaxf(lmax, __shfl_xor(lmax, off, 64));
    }

    __shared__ float s_v[4];
    __shared__ int   s_i[4];
    __shared__ float s_m[4];
    __shared__ int   s_bi;
    __shared__ float s_lm;
    __shared__ float s_sum[4];

    if (lane == 0) { s_v[wave] = smax; s_i[wave] = sidx; s_m[wave] = lmax; }
    __syncthreads();
    if (t == 0) {
        float bv = s_v[0]; int bi = s_i[0]; float bm = s_m[0];
        #pragma unroll
        for (int w = 1; w < 4; ++w) {
            if (s_v[w] > bv || (s_v[w] == bv && s_i[w] < bi)) { bv = s_v[w]; bi = s_i[w]; }
            bm = fmaxf(bm, s_m[w]);
        }
        s_bi = bi; s_lm = bm;
    }
    __syncthreads();
    const int   ind = s_bi;
    const float m   = s_lm;

    // ---- softmax(logits) denominator ----
    float e[4];
    float psum = 0.f;
    #pragma unroll
    for (int j = 0; j < 4; ++j) { e[j] = expf(lv[j] - m); psum += e[j]; }
    #pragma unroll
    for (int off = 32; off > 0; off >>= 1) psum += __shfl_xor(psum, off, 64);
    if (lane == 0) s_sum[wave] = psum;
    __syncthreads();
    const float sum = s_sum[0] + s_sum[1] + s_sum[2] + s_sum[3];
    const float inv = 1.0f / sum;

    // ---- diff = -log(qy*N + eps) / qy ----
    float d[4];
    #pragma unroll
    for (int j = 0; j < 4; ++j) {
        const float qy = e[j] * inv;
        d[j] = -logf(qy * (float)N_EMB + EPS_Q) / qy;
    }
    ((float4*)(diff + rbase))[t] = make_float4(d[0], d[1], d[2], d[3]);

    // ---- z_q row = embed[ind] (512 floats, float2 per thread) ----
    const float2* erow = (const float2*)(embed + (size_t)ind * D_EMB);
    float2*       zrow = (float2*)(zq + (size_t)row * D_EMB);
    zrow[t] = erow[t];

    if (t == 0) indf[row] = (float)ind;
}

extern "C" void kernel_launch(void* const* d_in, const int* in_sizes, int n_in,
                              void* d_out, int out_size, void* d_ws, size_t ws_size,
                              hipStream_t stream) {
    const float* logits = (const float*)d_in[0];
    const float* u      = (const float*)d_in[1];
    const float* embed  = (const float*)d_in[2];

    const int rows = in_sizes[0] / N_EMB;   // 8*2048 = 16384

    float* out  = (float*)d_out;
    float* zq   = out;                                   // rows*512
    float* diff = zq + (size_t)rows * D_EMB;             // rows*1024
    float* indf = diff + (size_t)rows * N_EMB;           // rows

    gumbel_quantize_kernel<<<rows, 256, 0, stream>>>(logits, u, embed, zq, diff, indf);
}